// Round 3
// baseline (718.601 us; speedup 1.0000x reference)
//
#include <hip/hip_runtime.h>
#include <hip/hip_bf16.h>
#include <math.h>

typedef __bf16 bf16_t;
typedef __bf16 bf16x4 __attribute__((ext_vector_type(4)));
typedef __bf16 bf16x8 __attribute__((ext_vector_type(8)));
typedef float  f32x4  __attribute__((ext_vector_type(4)));

#define QKV_SCALE 0.17677669529663687f   // 32^-0.5

// workspace offsets (bytes)
#define WS_QKVWT   0u          // [384][128] bf16, row n = original col (Q cols pre-scaled)
#define WS_PROJWT  98304u      // [128][128] bf16
#define WS_QKVB    131072u     // [384] f32 (Q entries pre-scaled)
#define WS_BM      135168u     // [256][64][64] f32  (mask + mlp bias, padded)

// ---------------------------------------------------------------- prep ----
__global__ __launch_bounds__(256) void prep_kernel(
    const float* __restrict__ mask,
    const float* __restrict__ qkv_w, const float* __restrict__ qkv_b,
    const float* __restrict__ mlp_w1, const float* __restrict__ mlp_b1,
    const float* __restrict__ mlp_w2, const float* __restrict__ mlp_b2,
    const float* __restrict__ proj_w,
    bf16_t* __restrict__ qkv_wT, bf16_t* __restrict__ proj_wT,
    float* __restrict__ qkv_bs, float* __restrict__ bm)
{
    const int blk = blockIdx.x;
    const int tid = threadIdx.x;
    if (blk < 16) {
        // bias+mask table, [wi*4+h][q(64)][kk(64)]
        const int cell = blk * 256 + tid;          // 0..4095
        const int q = cell >> 6, kk = cell & 63;
        if (q < 49 && kk < 49) {
            const float dy = (float)(q / 7 - kk / 7) * (1.0f / 6.0f);
            const float dx = (float)(q % 7 - kk % 7) * (1.0f / 6.0f);
            float b0 = mlp_b2[0], b1 = mlp_b2[1], b2 = mlp_b2[2], b3 = mlp_b2[3];
            for (int j = 0; j < 64; ++j) {
                const float pre = dy * mlp_w1[j] + dx * mlp_w1[64 + j] + mlp_b1[j];
                const float g = 0.5f * pre * (1.0f + erff(pre * 0.70710678118654752f));
                b0 += g * mlp_w2[j * 4 + 0];
                b1 += g * mlp_w2[j * 4 + 1];
                b2 += g * mlp_w2[j * 4 + 2];
                b3 += g * mlp_w2[j * 4 + 3];
            }
            const int nm = q * 49 + kk;
            for (int wi = 0; wi < 64; ++wi) {
                const float mv = mask[wi * 2401 + nm];
                bm[(size_t)((wi * 4 + 0) << 12) + cell] = mv + b0;
                bm[(size_t)((wi * 4 + 1) << 12) + cell] = mv + b1;
                bm[(size_t)((wi * 4 + 2) << 12) + cell] = mv + b2;
                bm[(size_t)((wi * 4 + 3) << 12) + cell] = mv + b3;
            }
        } else {
            const float val = (kk >= 49) ? -3.0e38f : 0.0f;   // kk-pad masked out; q-pad rows harmless
            for (int t = 0; t < 256; ++t)
                bm[(size_t)(t << 12) + cell] = val;
        }
    } else if (blk < 208) {
        const int idx = (blk - 16) * 256 + tid;    // 0..49151
        const int n = idx >> 7, k = idx & 127;
        float v = qkv_w[k * 384 + n];
        if (n < 128) v *= QKV_SCALE;               // fold Q scale into weights
        qkv_wT[idx] = (bf16_t)v;
    } else if (blk < 272) {
        const int idx = (blk - 208) * 256 + tid;   // 0..16383
        const int n = idx >> 7, k = idx & 127;
        proj_wT[idx] = (bf16_t)proj_w[k * 128 + n];
    } else {
        if (tid < 384) {
            float v = qkv_b[tid];
            if (tid < 128) v *= QKV_SCALE;
            qkv_bs[tid] = v;
        }
    }
}

// ---------------------------------------------------------------- main ----
// LDS (49152 B): per-wave region at w*12288:
//   [0,8192)    : qk [64 tok][64 col] bf16 (Q cols 0-31, K cols 32-63) -> later P [64 q][64 kk]
//   [8192,12288): vt [32 dim][64 tok] bf16
// os [64 tok][128 dim] bf16 (16 KiB) overlays smem[0..16384) after barrier.
// swizzle: byte ^= ((row&7)<<4) on write AND read (rule #21); row ≡ c16 (mod 16) everywhere.
__global__ __launch_bounds__(256, 3) void swin_main_kernel(
    const float* __restrict__ x,
    const bf16_t* __restrict__ qkv_wT,
    const bf16_t* __restrict__ proj_wT,
    const float* __restrict__ qkv_bs,
    const float* __restrict__ proj_b,
    const float* __restrict__ bm,
    float* __restrict__ out)
{
    __shared__ __align__(16) unsigned char smem[49152];

    const int b    = blockIdx.x;
    const int tid  = threadIdx.x;
    const int w    = tid >> 6;          // wave = head
    const int lane = tid & 63;
    const int c16  = lane & 15;
    const int q4   = lane >> 4;
    const int WB   = w * 12288;
    const int VB   = WB + 8192;
    const int swz  = (c16 & 7) << 4;    // row-swizzle term (rows ≡ c16 mod 16 everywhere)
    const float* xg = x + (size_t)b * 6272;

    const f32x4 zf = {0.f, 0.f, 0.f, 0.f};

    // ---- GEMM1 (fused QK-transposed + V-natural), x read direct from global ----
    f32x4 qk[4][4];     // [ocol-tile: Q0,Q1,K0,K1][token-tile]
    f32x4 va[4][2];     // [token-tile][vcol-tile]
#pragma unroll
    for (int mt = 0; mt < 4; ++mt) {
#pragma unroll
        for (int nt = 0; nt < 4; ++nt) qk[mt][nt] = zf;
        va[mt][0] = zf; va[mt][1] = zf;
    }
    const int colQK[4] = {32 * w, 32 * w + 16, 128 + 32 * w, 128 + 32 * w + 16};
    bool tv[4];
#pragma unroll
    for (int nt = 0; nt < 4; ++nt) tv[nt] = (c16 + 16 * nt) < 49;

#pragma unroll
    for (int ks = 0; ks < 4; ++ks) {
        bf16x8 xf[4];
#pragma unroll
        for (int nt = 0; nt < 4; ++nt) {
            if (tv[nt]) {
                const float* p = xg + (c16 + 16 * nt) * 128 + ks * 32 + q4 * 8;
                float4 a0 = *(const float4*)p;
                float4 a1 = *(const float4*)(p + 4);
                xf[nt][0] = (bf16_t)a0.x; xf[nt][1] = (bf16_t)a0.y;
                xf[nt][2] = (bf16_t)a0.z; xf[nt][3] = (bf16_t)a0.w;
                xf[nt][4] = (bf16_t)a1.x; xf[nt][5] = (bf16_t)a1.y;
                xf[nt][6] = (bf16_t)a1.z; xf[nt][7] = (bf16_t)a1.w;
            } else {
#pragma unroll
                for (int j = 0; j < 8; ++j) xf[nt][j] = (bf16_t)0.0f;
            }
        }
#pragma unroll
        for (int mt = 0; mt < 4; ++mt) {
            const bf16x8 wf = *(const bf16x8*)(qkv_wT + (colQK[mt] + c16) * 128 + ks * 32 + q4 * 8);
#pragma unroll
            for (int nt = 0; nt < 4; ++nt)
                qk[mt][nt] = __builtin_amdgcn_mfma_f32_16x16x32_bf16(wf, xf[nt], qk[mt][nt], 0, 0, 0);
        }
#pragma unroll
        for (int nt = 0; nt < 2; ++nt) {
            const bf16x8 vf = *(const bf16x8*)(qkv_wT + (256 + 32 * w + 16 * nt + c16) * 128 + ks * 32 + q4 * 8);
#pragma unroll
            for (int mt = 0; mt < 4; ++mt)
                va[mt][nt] = __builtin_amdgcn_mfma_f32_16x16x32_bf16(xf[mt], vf, va[mt][nt], 0, 0, 0);
        }
    }

    // ---- epilogue: Q/K (packed b64, [token][dim]) ----
#pragma unroll
    for (int mt = 0; mt < 4; ++mt) {
        const float4 qb = *(const float4*)(qkv_bs + colQK[mt] + 4 * q4);
        const int dim0 = (mt < 2 ? 16 * mt : 32 + 16 * (mt - 2)) + 4 * q4;
#pragma unroll
        for (int nt = 0; nt < 4; ++nt) {
            const int tok = c16 + 16 * nt;
            bf16x4 pk;
            pk[0] = (bf16_t)(qk[mt][nt][0] + qb.x);
            pk[1] = (bf16_t)(qk[mt][nt][1] + qb.y);
            pk[2] = (bf16_t)(qk[mt][nt][2] + qb.z);
            pk[3] = (bf16_t)(qk[mt][nt][3] + qb.w);
            *(bf16x4*)&smem[(WB + tok * 128 + dim0 * 2) ^ swz] = pk;
        }
    }
    // ---- epilogue: V -> vt (packed b64, [dim][token]) ----
#pragma unroll
    for (int nt = 0; nt < 2; ++nt) {
        const float qv = qkv_bs[256 + 32 * w + 16 * nt + c16];
        const int dim = c16 + 16 * nt;
#pragma unroll
        for (int mt = 0; mt < 4; ++mt) {
            const int tok0 = 16 * mt + 4 * q4;
            bf16x4 pk;
            pk[0] = (bf16_t)(va[mt][nt][0] + qv);
            pk[1] = (bf16_t)(va[mt][nt][1] + qv);
            pk[2] = (bf16_t)(va[mt][nt][2] + qv);
            pk[3] = (bf16_t)(va[mt][nt][3] + qv);
            *(bf16x4*)&smem[(VB + dim * 128 + tok0 * 2) ^ swz] = pk;
        }
    }

    // ---- S^T = K·Q^T : D[kk][q] (wave-private, no barrier) ----
    f32x4 st[4][4];     // [kk-tile][q-tile]
    {
        bf16x8 ka[4], qb_[4];
#pragma unroll
        for (int mt = 0; mt < 4; ++mt)
            ka[mt] = *(const bf16x8*)&smem[(WB + (c16 + 16 * mt) * 128 + 64 + 16 * q4) ^ swz];
#pragma unroll
        for (int nt = 0; nt < 4; ++nt)
            qb_[nt] = *(const bf16x8*)&smem[(WB + (c16 + 16 * nt) * 128 + 16 * q4) ^ swz];
#pragma unroll
        for (int mt = 0; mt < 4; ++mt)
#pragma unroll
            for (int nt = 0; nt < 4; ++nt)
                st[mt][nt] = __builtin_amdgcn_mfma_f32_16x16x32_bf16(ka[mt], qb_[nt], zf, 0, 0, 0),
                st[mt][nt] = st[mt][nt]; // single K-step
    }

    // ---- bias/mask add + softmax (per lane: q = c16+16nt) + P write (pre-normalized) ----
    const float* bq = bm + ((size_t)(((b & 63) << 2) + w) << 12);
#pragma unroll
    for (int nt = 0; nt < 4; ++nt) {
        const int q = c16 + 16 * nt;
        float4 bv[4];
#pragma unroll
        for (int mt = 0; mt < 4; ++mt)
            bv[mt] = *(const float4*)(bq + q * 64 + 16 * mt + 4 * q4);
        float mx = -3.0e38f;
#pragma unroll
        for (int mt = 0; mt < 4; ++mt) {
            st[mt][nt][0] += bv[mt].x; st[mt][nt][1] += bv[mt].y;
            st[mt][nt][2] += bv[mt].z; st[mt][nt][3] += bv[mt].w;
#pragma unroll
            for (int r = 0; r < 4; ++r) mx = fmaxf(mx, st[mt][nt][r]);
        }
        mx = fmaxf(mx, __shfl_xor(mx, 16));
        mx = fmaxf(mx, __shfl_xor(mx, 32));
        float sm = 0.0f;
#pragma unroll
        for (int mt = 0; mt < 4; ++mt)
#pragma unroll
            for (int r = 0; r < 4; ++r) {
                const float p = __expf(st[mt][nt][r] - mx);
                st[mt][nt][r] = p;
                sm += p;
            }
        sm += __shfl_xor(sm, 16);
        sm += __shfl_xor(sm, 32);
        const float rp = 1.0f / sm;
#pragma unroll
        for (int mt = 0; mt < 4; ++mt) {
            bf16x4 pk;
#pragma unroll
            for (int r = 0; r < 4; ++r) pk[r] = (bf16_t)(st[mt][nt][r] * rp);
            *(bf16x4*)&smem[(WB + q * 128 + (16 * mt + 4 * q4) * 2) ^ swz] = pk;
        }
    }

    // ---- PV as O^T: D[d][q] = vt · P^T ----
    f32x4 ot[2][4];
#pragma unroll
    for (int mt = 0; mt < 2; ++mt)
#pragma unroll
        for (int nt = 0; nt < 4; ++nt) ot[mt][nt] = zf;
#pragma unroll
    for (int ksv = 0; ksv < 2; ++ksv) {
        bf16x8 av[2], bp[4];
#pragma unroll
        for (int mt = 0; mt < 2; ++mt)
            av[mt] = *(const bf16x8*)&smem[(VB + (c16 + 16 * mt) * 128 + 64 * ksv + 16 * q4) ^ swz];
#pragma unroll
        for (int nt = 0; nt < 4; ++nt)
            bp[nt] = *(const bf16x8*)&smem[(WB + (c16 + 16 * nt) * 128 + 64 * ksv + 16 * q4) ^ swz];
#pragma unroll
        for (int mt = 0; mt < 2; ++mt)
#pragma unroll
            for (int nt = 0; nt < 4; ++nt)
                ot[mt][nt] = __builtin_amdgcn_mfma_f32_16x16x32_bf16(av[mt], bp[nt], ot[mt][nt], 0, 0, 0);
    }

    __syncthreads();    // all waves done reading their P/vt -> safe to overlay os

    // ---- O^T -> os [token][128], packed b64 ----
#pragma unroll
    for (int mt = 0; mt < 2; ++mt)
#pragma unroll
        for (int nt = 0; nt < 4; ++nt) {
            const int q = c16 + 16 * nt;
            bf16x4 pk;
#pragma unroll
            for (int r = 0; r < 4; ++r) pk[r] = (bf16_t)ot[mt][nt][r];
            *(bf16x4*)&smem[(q * 256 + (32 * w + 16 * mt + 4 * q4) * 2) ^ swz] = pk;
        }
    __syncthreads();

    // ---- proj as Y^T: D[ocol][token] = Wp^T · os^T ----
    f32x4 pj[2][4];
#pragma unroll
    for (int mt = 0; mt < 2; ++mt)
#pragma unroll
        for (int nt = 0; nt < 4; ++nt) pj[mt][nt] = zf;
#pragma unroll
    for (int ks = 0; ks < 4; ++ks) {
        bf16x8 aw[2], bo[4];
#pragma unroll
        for (int mt = 0; mt < 2; ++mt)
            aw[mt] = *(const bf16x8*)(proj_wT + (32 * w + 16 * mt + c16) * 128 + ks * 32 + q4 * 8);
#pragma unroll
        for (int nt = 0; nt < 4; ++nt)
            bo[nt] = *(const bf16x8*)&smem[((c16 + 16 * nt) * 256 + 64 * ks + 16 * q4) ^ swz];
#pragma unroll
        for (int mt = 0; mt < 2; ++mt)
#pragma unroll
            for (int nt = 0; nt < 4; ++nt)
                pj[mt][nt] = __builtin_amdgcn_mfma_f32_16x16x32_bf16(aw[mt], bo[nt], pj[mt][nt], 0, 0, 0);
    }

    // ---- epilogue: +proj_b, float4 stores ----
    float* og = out + (size_t)b * 6272;
#pragma unroll
    for (int mt = 0; mt < 2; ++mt) {
        const int oc0 = 32 * w + 16 * mt + 4 * q4;
        const float4 pb = *(const float4*)(proj_b + oc0);
#pragma unroll
        for (int nt = 0; nt < 4; ++nt) {
            const int tok = c16 + 16 * nt;
            if (tok < 49) {
                float4 v;
                v.x = pj[mt][nt][0] + pb.x;
                v.y = pj[mt][nt][1] + pb.y;
                v.z = pj[mt][nt][2] + pb.z;
                v.w = pj[mt][nt][3] + pb.w;
                *(float4*)(og + tok * 128 + oc0) = v;
            }
        }
    }
}

// -------------------------------------------------------------- launch ----
extern "C" void kernel_launch(void* const* d_in, const int* in_sizes, int n_in,
                              void* d_out, int out_size, void* d_ws, size_t ws_size,
                              hipStream_t stream) {
    const float* x      = (const float*)d_in[0];
    const float* mask   = (const float*)d_in[1];
    const float* qkv_w  = (const float*)d_in[2];
    const float* qkv_b  = (const float*)d_in[3];
    const float* mlp_w1 = (const float*)d_in[4];
    const float* mlp_b1 = (const float*)d_in[5];
    const float* mlp_w2 = (const float*)d_in[6];
    const float* mlp_b2 = (const float*)d_in[7];
    const float* proj_w = (const float*)d_in[8];
    const float* proj_b = (const float*)d_in[9];
    float* out = (float*)d_out;

    unsigned char* ws = (unsigned char*)d_ws;
    bf16_t* qkv_wT  = (bf16_t*)(ws + WS_QKVWT);
    bf16_t* proj_wT = (bf16_t*)(ws + WS_PROJWT);
    float*  qkv_bs  = (float*)(ws + WS_QKVB);
    float*  bm      = (float*)(ws + WS_BM);

    hipLaunchKernelGGL(prep_kernel, dim3(273), dim3(256), 0, stream,
                       mask, qkv_w, qkv_b, mlp_w1, mlp_b1, mlp_w2, mlp_b2, proj_w,
                       qkv_wT, proj_wT, qkv_bs, bm);
    hipLaunchKernelGGL(swin_main_kernel, dim3(16384), dim3(256), 0, stream,
                       x, qkv_wT, proj_wT, qkv_bs, proj_b, bm, out);
}